// Round 7
// baseline (312.299 us; speedup 1.0000x reference)
//
#include <hip/hip_runtime.h>

#define NN 50000
#define EE 800000
#define ET (EE + NN)

typedef unsigned short ushort_t;

__device__ __forceinline__ float bf2f(ushort_t u) {
    return __uint_as_float(((unsigned int)u) << 16);
}
__device__ __forceinline__ ushort_t f2bf(float f) {
    unsigned int u = __float_as_uint(f);
    u += 0x7fffu + ((u >> 16) & 1u);
    return (ushort_t)(u >> 16);
}
__device__ __forceinline__ float lrelu(float e) {
    return fmaxf(e, 0.f) + 0.2f * fminf(e, 0.f);
}
// load float input that may be fp32 or bf16, per sniffed flag
__device__ __forceinline__ float ldf(const void* p, int i, bool f32) {
    return f32 ? ((const float*)p)[i] : bf2f(((const ushort_t*)p)[i]);
}

// ---------------- dtype sniffer: flags[0]=float inputs are fp32, flags[1]=edge_index is int64 ----------------
__global__ __launch_bounds__(256) void sniff_kernel(const unsigned int* xw, const int* eiw, int* flags) {
    __shared__ int cnt0, cnt1;
    int t = threadIdx.x;
    if (t == 0) { cnt0 = 0; cnt1 = 0; }
    __syncthreads();
    float v = __uint_as_float(xw[t]);
    float a = fabsf(v);
    if ((a > 1e-6f && a < 1e6f) || v == 0.f) atomicAdd(&cnt0, 1);
    if (eiw[2 * t + 1] != 0) atomicAdd(&cnt1, 1);
    __syncthreads();
    if (t == 0) {
        flags[0] = (cnt0 >= 192) ? 1 : 0;
        flags[1] = (cnt1 <= 16) ? 1 : 0;
    }
}

// ---------------- CSR build ----------------
__device__ __forceinline__ void edge_sd(const int* ei, int i, bool i64, int& s, int& d) {
    if (i < EE) {
        if (i64) { s = ei[2 * i]; d = ei[2 * (EE + i)]; }
        else     { s = ei[i];     d = ei[EE + i]; }
    } else {
        s = d = i - EE;
    }
}

// degree + rank in one pass; 8 XCD-local histogram slices (g = blockIdx&7 tracks the
// hardware's round-robin blockIdx->XCD map) so atomic lines stay in one L2.
__global__ __launch_bounds__(256) void degree_rank_kernel(const int* ei, int* deg8, int* rank, const int* flags) {
    int i = blockIdx.x * 256 + threadIdx.x;
    if (i >= ET) return;
    bool i64 = flags[1] != 0;
    int g = blockIdx.x & 7;
    int s, d;
    edge_sd(ei, i, i64, s, d);
    rank[i] = atomicAdd(&deg8[(size_t)g * NN + d], 1);
}

// single-block scan; transforms deg8 counts -> absolute segment offsets in-place, writes rowptr
__global__ __launch_bounds__(1024) void scan_kernel(int* deg8, int* rowptr) {
    __shared__ int wsum[16];
    __shared__ int carry;
    if (threadIdx.x == 0) carry = 0;
    __syncthreads();
    int t = threadIdx.x;
    int lane = t & 63, wid = t >> 6;
    const int NI = NN / 4;
    for (int base = 0; base < NI; base += 1024) {
        int i4 = base + t;
        int4 dv[8];
        int v = 0;
        if (i4 < NI) {
            #pragma unroll
            for (int g = 0; g < 8; ++g) {
                dv[g] = ((const int4*)(deg8 + (size_t)g * NN))[i4];
                v += dv[g].x + dv[g].y + dv[g].z + dv[g].w;
            }
        } else {
            #pragma unroll
            for (int g = 0; g < 8; ++g) dv[g] = make_int4(0, 0, 0, 0);
        }
        int x = v;
        #pragma unroll
        for (int off = 1; off < 64; off <<= 1) {
            int y = __shfl_up(x, off);
            if (lane >= off) x += y;
        }
        if (lane == 63) wsum[wid] = x;
        __syncthreads();
        if (t < 16) {
            int s = wsum[t];
            #pragma unroll
            for (int off = 1; off < 16; off <<= 1) {
                int y = __shfl_up(s, off);
                if (t >= off) s += y;
            }
            wsum[t] = s;
        }
        __syncthreads();
        int woff = ((wid > 0) ? wsum[wid - 1] : 0) + carry;
        int excl = x - v + woff;
        if (i4 < NI) {
            int run = excl;
            int4 ov[8];
            int4 rp;
            #pragma unroll
            for (int j = 0; j < 4; ++j) {
                (&rp.x)[j] = run;
                #pragma unroll
                for (int g = 0; g < 8; ++g) {
                    (&ov[g].x)[j] = run;
                    run += (&dv[g].x)[j];
                }
            }
            ((int4*)rowptr)[i4] = rp;
            #pragma unroll
            for (int g = 0; g < 8; ++g)
                ((int4*)(deg8 + (size_t)g * NN))[i4] = ov[g];
        }
        int ct = wsum[15];
        __syncthreads();
        if (t == 0) carry += ct;
        __syncthreads();
    }
    if (threadIdx.x == 0) rowptr[NN] = carry;
}

// atomic-free fill: pos = deg8off[g][d] + rank[i] (same blockIdx->g map as degree_rank)
__global__ __launch_bounds__(256) void fill_kernel(const int* ei, const int* deg8off, const int* rank,
                                                   int* col, const int* flags) {
    int i = blockIdx.x * 256 + threadIdx.x;
    if (i >= ET) return;
    bool i64 = flags[1] != 0;
    int g = blockIdx.x & 7;
    int s, d;
    edge_sd(ei, i, i64, s, d);
    col[deg8off[(size_t)g * NN + d] + rank[i]] = s;
}

// ---------------- GEMM + fused alpha epilogue ----------------
#define FMA4(accv, wv, xs)                   \
    accv.x = fmaf(wv.x, xs, accv.x);         \
    accv.y = fmaf(wv.y, xs, accv.y);         \
    accv.z = fmaf(wv.z, xs, accv.z);         \
    accv.w = fmaf(wv.w, xs, accv.w);

template <bool AEXT, int NH>
__global__ __launch_bounds__(256) void gemm64_kernel(const void* Av, const void* Wv,
                                                     const void* a_src, const void* a_dst,
                                                     ushort_t* outb, float* asrc, float* adst,
                                                     int n, int wstride, int ostride,
                                                     const int* flags) {
    __shared__ __align__(16) float Wf[128 * 64];
    __shared__ __align__(16) float xT[128 * 64];  // xT[k][r]
    bool f32 = flags[0] != 0;
    int t = threadIdx.x;
    int coloff = blockIdx.y * 64;

    // ---- stage W -> fp32 LDS ----
    if (f32) {
        const float* W = (const float*)Wv;
        for (int i = t; i < 2048; i += 256) {
            int k = i >> 4;
            int cp = i & 15;
            float4 wv = *(const float4*)(W + k * wstride + coloff + cp * 4);
            *(float4*)(&Wf[k * 64 + cp * 4]) = wv;
        }
    } else {
        const ushort_t* W = (const ushort_t*)Wv;
        for (int i = t; i < 4096; i += 256) {
            int k = i >> 5;
            int cp = i & 31;
            unsigned int v = *(const unsigned int*)(W + k * wstride + coloff + cp * 2);
            float2 w2 = make_float2(__uint_as_float(v << 16), __uint_as_float(v & 0xffff0000u));
            *(float2*)(&Wf[k * 64 + cp * 2]) = w2;
        }
    }

    // ---- stage A tile (64 rows) transposed ----
    int base = blockIdx.x * 64;
    int r = t & 63;
    int kc = t >> 6;
    int row = base + r;
    if (AEXT && !f32) {
        if (row < n) {
            const uint4* p = (const uint4*)((const ushort_t*)Av + (size_t)row * 128 + kc * 32);
            #pragma unroll
            for (int j = 0; j < 4; ++j) {
                uint4 q = p[j];
                int kb = kc * 32 + j * 8;
                xT[(kb + 0) * 64 + r] = __uint_as_float(q.x << 16);
                xT[(kb + 1) * 64 + r] = __uint_as_float(q.x & 0xffff0000u);
                xT[(kb + 2) * 64 + r] = __uint_as_float(q.y << 16);
                xT[(kb + 3) * 64 + r] = __uint_as_float(q.y & 0xffff0000u);
                xT[(kb + 4) * 64 + r] = __uint_as_float(q.z << 16);
                xT[(kb + 5) * 64 + r] = __uint_as_float(q.z & 0xffff0000u);
                xT[(kb + 6) * 64 + r] = __uint_as_float(q.w << 16);
                xT[(kb + 7) * 64 + r] = __uint_as_float(q.w & 0xffff0000u);
            }
        } else {
            #pragma unroll
            for (int j = 0; j < 32; ++j) xT[(kc * 32 + j) * 64 + r] = 0.f;
        }
    } else {
        if (row < n) {
            const float4* p = (const float4*)((const float*)Av + (size_t)row * 128 + kc * 32);
            #pragma unroll
            for (int j = 0; j < 8; ++j) {
                float4 q = p[j];
                int kb = kc * 32 + j * 4;
                xT[(kb + 0) * 64 + r] = q.x;
                xT[(kb + 1) * 64 + r] = q.y;
                xT[(kb + 2) * 64 + r] = q.z;
                xT[(kb + 3) * 64 + r] = q.w;
            }
        } else {
            #pragma unroll
            for (int j = 0; j < 32; ++j) xT[(kc * 32 + j) * 64 + r] = 0.f;
        }
    }
    __syncthreads();

    // ---- compute: thread = (cg, rg): cols cg*4..+3, rows rg*4..+3 ----
    int cg = t & 15, rg = t >> 4;
    const float4* W4 = (const float4*)Wf;
    const float4* X4 = (const float4*)xT;
    float4 a0 = make_float4(0, 0, 0, 0), a1 = a0, a2 = a0, a3 = a0;
    #pragma unroll 4
    for (int k = 0; k < 128; ++k) {
        float4 wv = W4[k * 16 + cg];
        float4 xv = X4[k * 16 + rg];
        FMA4(a0, wv, xv.x)
        FMA4(a1, wv, xv.y)
        FMA4(a2, wv, xv.z)
        FMA4(a3, wv, xv.w)
    }

    // ---- epilogue 1: bf16 store of h tile ----
    int orow = base + rg * 4;
    int c0 = coloff + cg * 4;
    float4 av[4] = {a0, a1, a2, a3};
    #pragma unroll
    for (int j = 0; j < 4; ++j) {
        if (orow + j < n) {
            ushort4 o4;
            o4.x = f2bf(av[j].x); o4.y = f2bf(av[j].y);
            o4.z = f2bf(av[j].z); o4.w = f2bf(av[j].w);
            *(ushort4*)(outb + (size_t)(orow + j) * ostride + c0) = o4;
        }
    }

    // ---- epilogue 2: fused alpha dot products ----
    float4 avs, avd;
    avs.x = ldf(a_src, c0 + 0, f32); avs.y = ldf(a_src, c0 + 1, f32);
    avs.z = ldf(a_src, c0 + 2, f32); avs.w = ldf(a_src, c0 + 3, f32);
    avd.x = ldf(a_dst, c0 + 0, f32); avd.y = ldf(a_dst, c0 + 1, f32);
    avd.z = ldf(a_dst, c0 + 2, f32); avd.w = ldf(a_dst, c0 + 3, f32);
    float ps[4], pd[4];
    #pragma unroll
    for (int j = 0; j < 4; ++j) {
        ps[j] = av[j].x * avs.x + av[j].y * avs.y + av[j].z * avs.z + av[j].w * avs.w;
        pd[j] = av[j].x * avd.x + av[j].y * avd.y + av[j].z * avd.z + av[j].w * avd.w;
    }
    const int span = (NH == 8) ? 4 : 16;
    #pragma unroll
    for (int stp = 1; stp < span; stp <<= 1) {
        #pragma unroll
        for (int j = 0; j < 4; ++j) {
            ps[j] += __shfl_xor(ps[j], stp);
            pd[j] += __shfl_xor(pd[j], stp);
        }
    }
    if ((cg & (span - 1)) == 0) {
        int hh = (NH == 8) ? (coloff / 16 + (cg >> 2)) : 0;
        #pragma unroll
        for (int j = 0; j < 4; ++j) {
            int rw = orow + j;
            if (rw < n) {
                asrc[(size_t)rw * NH + hh] = ps[j];
                adst[(size_t)rw * NH + hh] = pd[j];
            }
        }
    }
}

// ---------------- layer-1 aggregation: one wave per dst node, two-phase pipelined gather ----------------
__global__ __launch_bounds__(256) void agg1_kernel(const int* __restrict__ rowptr, const int* __restrict__ col,
                                                   const ushort_t* __restrict__ h1b,
                                                   const float* __restrict__ asrc, const float* __restrict__ adst,
                                                   const void* b1, float* __restrict__ hmid, const int* flags) {
    __shared__ float wle[4][8 * 72];
    __shared__ int loff[4][64];
    bool f32 = flags[0] != 0;
    int lane = threadIdx.x & 63, wid = threadIdx.x >> 6;
    int d = blockIdx.x * 4 + wid;
    if (d >= NN) return;                 // per-wave LDS only; no __syncthreads in this kernel
    int start = rowptr[d], end = rowptr[d + 1];
    int hB = lane >> 3;                  // head of dims 2*lane, 2*lane+1
    const float4* dp = (const float4*)(adst + (size_t)d * 8);
    float4 ad0 = dp[0], ad1 = dp[1];     // wave-uniform broadcast load
    const char* hb = (const char*)h1b + lane * 4;   // lane offset hoisted out of loop
    float acc0 = 0.f, acc1 = 0.f, ssum = 0.f;
    for (int chunk = start; chunk < end; chunk += 64) {
        int cnt = min(64, end - chunk);
        int c = (chunk + lane < end) ? col[chunk + lane] : 0;
        loff[wid][lane] = c << 8;        // byte offset of 256B h1b row
        if (lane < cnt) {
            const float4* ap = (const float4*)(asrc + (size_t)c * 8);
            float4 s0 = ap[0], s1 = ap[1];
            wle[wid][0 * 72 + lane] = __expf(lrelu(s0.x + ad0.x));
            wle[wid][1 * 72 + lane] = __expf(lrelu(s0.y + ad0.y));
            wle[wid][2 * 72 + lane] = __expf(lrelu(s0.z + ad0.z));
            wle[wid][3 * 72 + lane] = __expf(lrelu(s0.w + ad0.w));
            wle[wid][4 * 72 + lane] = __expf(lrelu(s1.x + ad1.x));
            wle[wid][5 * 72 + lane] = __expf(lrelu(s1.y + ad1.y));
            wle[wid][6 * 72 + lane] = __expf(lrelu(s1.z + ad1.z));
            wle[wid][7 * 72 + lane] = __expf(lrelu(s1.w + ad1.w));
        }
        #pragma unroll 4
        for (int j = 0; j < cnt; ++j) {
            int off = loff[wid][j];
            float ex = wle[wid][hB * 72 + j];
            unsigned int hv = *(const unsigned int*)(hb + off);
            ssum += ex;
            acc0 = fmaf(ex, __uint_as_float(hv << 16), acc0);
            acc1 = fmaf(ex, __uint_as_float(hv & 0xffff0000u), acc1);
        }
    }
    float inv = 1.f / (ssum + 1e-16f);
    float o0 = fmaf(acc0, inv, ldf(b1, lane * 2, f32));
    float o1 = fmaf(acc1, inv, ldf(b1, lane * 2 + 1, f32));
    o0 = (o0 > 0.f) ? o0 : (__expf(o0) - 1.f);   // ELU
    o1 = (o1 > 0.f) ? o1 : (__expf(o1) - 1.f);
    *(float2*)(hmid + (size_t)d * 128 + lane * 2) = make_float2(o0, o1);
}

// ---------------- layer-2 aggregation (same two-phase scheme) + log_softmax; fp32 output ----------------
__global__ __launch_bounds__(256) void agg2_kernel(const int* __restrict__ rowptr, const int* __restrict__ col,
                                                   const ushort_t* __restrict__ h2b,
                                                   const float* __restrict__ asrc, const float* __restrict__ adst,
                                                   const void* b2, float* __restrict__ out, const int* flags) {
    __shared__ float wle[4][64];
    __shared__ int loff[4][64];
    bool f32 = flags[0] != 0;
    int lane = threadIdx.x & 63, wid = threadIdx.x >> 6;
    int d = blockIdx.x * 4 + wid;
    if (d >= NN) return;
    int start = rowptr[d], end = rowptr[d + 1];
    float ad = adst[d];
    const char* hb = (const char*)h2b + lane * 2;
    float acc = 0.f, ssum = 0.f;
    for (int chunk = start; chunk < end; chunk += 64) {
        int cnt = min(64, end - chunk);
        int c = (chunk + lane < end) ? col[chunk + lane] : 0;
        loff[wid][lane] = c << 7;        // byte offset of 128B h2b row
        if (lane < cnt) wle[wid][lane] = __expf(lrelu(asrc[c] + ad));
        #pragma unroll 4
        for (int j = 0; j < cnt; ++j) {
            int off = loff[wid][j];
            float ex = wle[wid][j];
            float hv = bf2f(*(const ushort_t*)(hb + off));
            ssum += ex;
            acc = fmaf(ex, hv, acc);
        }
    }
    float o = acc / (ssum + 1e-16f) + ldf(b2, lane, f32);
    // log_softmax across 64 lanes
    float mm = o;
    #pragma unroll
    for (int off = 1; off < 64; off <<= 1) mm = fmaxf(mm, __shfl_xor(mm, off));
    float texp = __expf(o - mm);
    float ts = texp;
    #pragma unroll
    for (int off = 1; off < 64; off <<= 1) ts += __shfl_xor(ts, off);
    float ls = o - mm - __logf(ts);
    out[(size_t)d * 64 + lane] = o;
    out[(size_t)NN * 64 + (size_t)d * 64 + lane] = ls;
}

extern "C" void kernel_launch(void* const* d_in, const int* in_sizes, int n_in,
                              void* d_out, int out_size, void* d_ws, size_t ws_size,
                              hipStream_t stream) {
    const void* x   = d_in[0];
    const int*  ei  = (const int*)d_in[1];
    const void* W1  = d_in[2];
    const void* as1 = d_in[3];
    const void* ad1 = d_in[4];
    const void* b1  = d_in[5];
    const void* W2  = d_in[6];
    const void* as2 = d_in[7];
    const void* ad2 = d_in[8];
    const void* b2  = d_in[9];
    float* out = (float*)d_out;

    char* w = (char*)d_ws;
    auto alloc = [&](size_t bytes) {
        void* p = (void*)w;
        w += (bytes + 255) & ~(size_t)255;
        return p;
    };
    int* flags    = (int*)alloc(256);
    int* deg8     = (int*)alloc((size_t)8 * NN * 4);
    int* rowptr   = (int*)alloc((size_t)(NN + 1) * 4);
    int* rank     = (int*)alloc((size_t)ET * 4);
    int* colx     = (int*)alloc((size_t)ET * 4);
    ushort_t* h1b = (ushort_t*)alloc((size_t)NN * 128 * 2);
    float* asrc1  = (float*)alloc((size_t)NN * 8 * 4);
    float* adst1  = (float*)alloc((size_t)NN * 8 * 4);
    float* hmid   = (float*)alloc((size_t)NN * 128 * 4);
    ushort_t* h2b = (ushort_t*)alloc((size_t)NN * 64 * 2);
    float* asrc2  = (float*)alloc((size_t)NN * 4);
    float* adst2  = (float*)alloc((size_t)NN * 4);

    sniff_kernel<<<1, 256, 0, stream>>>((const unsigned int*)x, ei, flags);

    hipMemsetAsync(deg8, 0, (size_t)8 * NN * 4, stream);
    degree_rank_kernel<<<(ET + 255) / 256, 256, 0, stream>>>(ei, deg8, rank, flags);
    scan_kernel<<<1, 1024, 0, stream>>>(deg8, rowptr);
    fill_kernel<<<(ET + 255) / 256, 256, 0, stream>>>(ei, deg8, rank, colx, flags);

    dim3 g1((NN + 63) / 64, 2);
    gemm64_kernel<true, 8><<<g1, 256, 0, stream>>>(x, W1, as1, ad1, h1b, asrc1, adst1, NN, 128, 128, flags);
    agg1_kernel<<<(NN + 3) / 4, 256, 0, stream>>>(rowptr, colx, h1b, asrc1, adst1, b1, hmid, flags);

    dim3 g2((NN + 63) / 64, 1);
    gemm64_kernel<false, 1><<<g2, 256, 0, stream>>>((const void*)hmid, W2, as2, ad2, h2b, asrc2, adst2, NN, 64, 64, flags);
    agg2_kernel<<<(NN + 3) / 4, 256, 0, stream>>>(rowptr, colx, h2b, asrc2, adst2, b2, out, flags);
}

// Round 8
// 274.885 us; speedup vs baseline: 1.1361x; 1.1361x over previous
//
#include <hip/hip_runtime.h>

#define NN 50000
#define EE 800000
#define ET (EE + NN)
#define NCH ((NN + 255) / 256)   // 196 chunks of 256 nodes

typedef unsigned short ushort_t;

__device__ __forceinline__ float bf2f(ushort_t u) {
    return __uint_as_float(((unsigned int)u) << 16);
}
__device__ __forceinline__ ushort_t f2bf(float f) {
    unsigned int u = __float_as_uint(f);
    u += 0x7fffu + ((u >> 16) & 1u);
    return (ushort_t)(u >> 16);
}
__device__ __forceinline__ float lrelu(float e) {
    return fmaxf(e, 0.f) + 0.2f * fminf(e, 0.f);
}
// load float input that may be fp32 or bf16, per sniffed flag
__device__ __forceinline__ float ldf(const void* p, int i, bool f32) {
    return f32 ? ((const float*)p)[i] : bf2f(((const ushort_t*)p)[i]);
}

// ---------------- dtype sniffer: flags[0]=float inputs are fp32, flags[1]=edge_index is int64 ----------------
__global__ __launch_bounds__(256) void sniff_kernel(const unsigned int* xw, const int* eiw, int* flags) {
    __shared__ int cnt0, cnt1;
    int t = threadIdx.x;
    if (t == 0) { cnt0 = 0; cnt1 = 0; }
    __syncthreads();
    float v = __uint_as_float(xw[t]);
    float a = fabsf(v);
    if ((a > 1e-6f && a < 1e6f) || v == 0.f) atomicAdd(&cnt0, 1);
    if (eiw[2 * t + 1] != 0) atomicAdd(&cnt1, 1);
    __syncthreads();
    if (t == 0) {
        flags[0] = (cnt0 >= 192) ? 1 : 0;
        flags[1] = (cnt1 <= 16) ? 1 : 0;
    }
}

// ---------------- CSR build ----------------
__device__ __forceinline__ void edge_sd(const int* ei, int i, bool i64, int& s, int& d) {
    if (i < EE) {
        if (i64) { s = ei[2 * i]; d = ei[2 * (EE + i)]; }
        else     { s = ei[i];     d = ei[EE + i]; }
    } else {
        s = d = i - EE;
    }
}

// degree + rank in one pass; 8 XCD-local histogram slices (g = blockIdx&7 tracks the
// hardware's round-robin blockIdx->XCD map) so atomic lines stay in one L2.
__global__ __launch_bounds__(256) void degree_rank_kernel(const int* ei, int* deg8, int* rank, const int* flags) {
    int i = blockIdx.x * 256 + threadIdx.x;
    if (i >= ET) return;
    bool i64 = flags[1] != 0;
    int g = blockIdx.x & 7;
    int s, d;
    edge_sd(ei, i, i64, s, d);
    rank[i] = atomicAdd(&deg8[(size_t)g * NN + d], 1);
}

// ---- 3-phase parallel scan over 196 chunks of 256 nodes ----
// A: per-chunk totals
__global__ __launch_bounds__(256) void scanA_kernel(const int* __restrict__ deg8, int* __restrict__ chunksum) {
    __shared__ int wsum[4];
    int t = threadIdx.x;
    int node = blockIdx.x * 256 + t;
    int v = 0;
    if (node < NN) {
        #pragma unroll
        for (int g = 0; g < 8; ++g) v += deg8[(size_t)g * NN + node];
    }
    int lane = t & 63, wid = t >> 6;
    #pragma unroll
    for (int off = 1; off < 64; off <<= 1) v += __shfl_xor(v, off);
    if (lane == 0) wsum[wid] = v;
    __syncthreads();
    if (t == 0) chunksum[blockIdx.x] = wsum[0] + wsum[1] + wsum[2] + wsum[3];
}

// B: single tiny block scans 196 chunk sums -> exclusive chunk offsets; writes rowptr[NN]
__global__ __launch_bounds__(256) void scanB_kernel(const int* __restrict__ chunksum, int* __restrict__ chunkoff,
                                                    int* __restrict__ rowptr) {
    __shared__ int wsum[4];
    int t = threadIdx.x;
    int lane = t & 63, wid = t >> 6;
    int v = (t < NCH) ? chunksum[t] : 0;
    int x = v;
    #pragma unroll
    for (int off = 1; off < 64; off <<= 1) {
        int y = __shfl_up(x, off);
        if (lane >= off) x += y;
    }
    if (lane == 63) wsum[wid] = x;
    __syncthreads();
    if (t < 4) {
        int s = wsum[t];
        #pragma unroll
        for (int off = 1; off < 4; off <<= 1) {
            int y = __shfl_up(s, off);
            if (t >= off) s += y;
        }
        wsum[t] = s;
    }
    __syncthreads();
    int incl = x + ((wid > 0) ? wsum[wid - 1] : 0);
    if (t < NCH) chunkoff[t] = incl - v;
    if (t == 255) rowptr[NN] = wsum[3];
}

// C: intra-chunk exclusive scan; writes rowptr and converts deg8 counts -> absolute offsets in place
__global__ __launch_bounds__(256) void scanC_kernel(int* __restrict__ deg8, int* __restrict__ rowptr,
                                                    const int* __restrict__ chunkoff) {
    __shared__ int wsum[4];
    int t = threadIdx.x;
    int node = blockIdx.x * 256 + t;
    int dv[8];
    int v = 0;
    if (node < NN) {
        #pragma unroll
        for (int g = 0; g < 8; ++g) {
            dv[g] = deg8[(size_t)g * NN + node];
            v += dv[g];
        }
    }
    int lane = t & 63, wid = t >> 6;
    int x = v;
    #pragma unroll
    for (int off = 1; off < 64; off <<= 1) {
        int y = __shfl_up(x, off);
        if (lane >= off) x += y;
    }
    if (lane == 63) wsum[wid] = x;
    __syncthreads();
    if (t < 4) {
        int s = wsum[t];
        #pragma unroll
        for (int off = 1; off < 4; off <<= 1) {
            int y = __shfl_up(s, off);
            if (t >= off) s += y;
        }
        wsum[t] = s;
    }
    __syncthreads();
    int excl = x - v + ((wid > 0) ? wsum[wid - 1] : 0);
    if (node < NN) {
        int run = chunkoff[blockIdx.x] + excl;
        rowptr[node] = run;
        #pragma unroll
        for (int g = 0; g < 8; ++g) {
            deg8[(size_t)g * NN + node] = run;
            run += dv[g];
        }
    }
}

// atomic-free fill: pos = deg8off[g][d] + rank[i] (same blockIdx->g map as degree_rank)
__global__ __launch_bounds__(256) void fill_kernel(const int* ei, const int* deg8off, const int* rank,
                                                   int* col, const int* flags) {
    int i = blockIdx.x * 256 + threadIdx.x;
    if (i >= ET) return;
    bool i64 = flags[1] != 0;
    int g = blockIdx.x & 7;
    int s, d;
    edge_sd(ei, i, i64, s, d);
    col[deg8off[(size_t)g * NN + d] + rank[i]] = s;
}

// ---------------- GEMM + fused alpha epilogue ----------------
#define FMA4(accv, wv, xs)                   \
    accv.x = fmaf(wv.x, xs, accv.x);         \
    accv.y = fmaf(wv.y, xs, accv.y);         \
    accv.z = fmaf(wv.z, xs, accv.z);         \
    accv.w = fmaf(wv.w, xs, accv.w);

template <bool AEXT, int NH>
__global__ __launch_bounds__(256) void gemm64_kernel(const void* Av, const void* Wv,
                                                     const void* a_src, const void* a_dst,
                                                     ushort_t* outb, float* asrc, float* adst,
                                                     int n, int wstride, int ostride,
                                                     const int* flags) {
    __shared__ __align__(16) float Wf[128 * 64];
    __shared__ __align__(16) float xT[128 * 64];  // xT[k][r]
    bool f32 = flags[0] != 0;
    int t = threadIdx.x;
    int coloff = blockIdx.y * 64;

    // ---- stage W -> fp32 LDS ----
    if (f32) {
        const float* W = (const float*)Wv;
        for (int i = t; i < 2048; i += 256) {
            int k = i >> 4;
            int cp = i & 15;
            float4 wv = *(const float4*)(W + k * wstride + coloff + cp * 4);
            *(float4*)(&Wf[k * 64 + cp * 4]) = wv;
        }
    } else {
        const ushort_t* W = (const ushort_t*)Wv;
        for (int i = t; i < 4096; i += 256) {
            int k = i >> 5;
            int cp = i & 31;
            unsigned int v = *(const unsigned int*)(W + k * wstride + coloff + cp * 2);
            float2 w2 = make_float2(__uint_as_float(v << 16), __uint_as_float(v & 0xffff0000u));
            *(float2*)(&Wf[k * 64 + cp * 2]) = w2;
        }
    }

    // ---- stage A tile (64 rows) transposed ----
    int base = blockIdx.x * 64;
    int r = t & 63;
    int kc = t >> 6;
    int row = base + r;
    if (AEXT && !f32) {
        if (row < n) {
            const uint4* p = (const uint4*)((const ushort_t*)Av + (size_t)row * 128 + kc * 32);
            #pragma unroll
            for (int j = 0; j < 4; ++j) {
                uint4 q = p[j];
                int kb = kc * 32 + j * 8;
                xT[(kb + 0) * 64 + r] = __uint_as_float(q.x << 16);
                xT[(kb + 1) * 64 + r] = __uint_as_float(q.x & 0xffff0000u);
                xT[(kb + 2) * 64 + r] = __uint_as_float(q.y << 16);
                xT[(kb + 3) * 64 + r] = __uint_as_float(q.y & 0xffff0000u);
                xT[(kb + 4) * 64 + r] = __uint_as_float(q.z << 16);
                xT[(kb + 5) * 64 + r] = __uint_as_float(q.z & 0xffff0000u);
                xT[(kb + 6) * 64 + r] = __uint_as_float(q.w << 16);
                xT[(kb + 7) * 64 + r] = __uint_as_float(q.w & 0xffff0000u);
            }
        } else {
            #pragma unroll
            for (int j = 0; j < 32; ++j) xT[(kc * 32 + j) * 64 + r] = 0.f;
        }
    } else {
        if (row < n) {
            const float4* p = (const float4*)((const float*)Av + (size_t)row * 128 + kc * 32);
            #pragma unroll
            for (int j = 0; j < 8; ++j) {
                float4 q = p[j];
                int kb = kc * 32 + j * 4;
                xT[(kb + 0) * 64 + r] = q.x;
                xT[(kb + 1) * 64 + r] = q.y;
                xT[(kb + 2) * 64 + r] = q.z;
                xT[(kb + 3) * 64 + r] = q.w;
            }
        } else {
            #pragma unroll
            for (int j = 0; j < 32; ++j) xT[(kc * 32 + j) * 64 + r] = 0.f;
        }
    }
    __syncthreads();

    // ---- compute: thread = (cg, rg): cols cg*4..+3, rows rg*4..+3 ----
    int cg = t & 15, rg = t >> 4;
    const float4* W4 = (const float4*)Wf;
    const float4* X4 = (const float4*)xT;
    float4 a0 = make_float4(0, 0, 0, 0), a1 = a0, a2 = a0, a3 = a0;
    #pragma unroll 4
    for (int k = 0; k < 128; ++k) {
        float4 wv = W4[k * 16 + cg];
        float4 xv = X4[k * 16 + rg];
        FMA4(a0, wv, xv.x)
        FMA4(a1, wv, xv.y)
        FMA4(a2, wv, xv.z)
        FMA4(a3, wv, xv.w)
    }

    // ---- epilogue 1: bf16 store of h tile ----
    int orow = base + rg * 4;
    int c0 = coloff + cg * 4;
    float4 av[4] = {a0, a1, a2, a3};
    #pragma unroll
    for (int j = 0; j < 4; ++j) {
        if (orow + j < n) {
            ushort4 o4;
            o4.x = f2bf(av[j].x); o4.y = f2bf(av[j].y);
            o4.z = f2bf(av[j].z); o4.w = f2bf(av[j].w);
            *(ushort4*)(outb + (size_t)(orow + j) * ostride + c0) = o4;
        }
    }

    // ---- epilogue 2: fused alpha dot products ----
    float4 avs, avd;
    avs.x = ldf(a_src, c0 + 0, f32); avs.y = ldf(a_src, c0 + 1, f32);
    avs.z = ldf(a_src, c0 + 2, f32); avs.w = ldf(a_src, c0 + 3, f32);
    avd.x = ldf(a_dst, c0 + 0, f32); avd.y = ldf(a_dst, c0 + 1, f32);
    avd.z = ldf(a_dst, c0 + 2, f32); avd.w = ldf(a_dst, c0 + 3, f32);
    float ps[4], pd[4];
    #pragma unroll
    for (int j = 0; j < 4; ++j) {
        ps[j] = av[j].x * avs.x + av[j].y * avs.y + av[j].z * avs.z + av[j].w * avs.w;
        pd[j] = av[j].x * avd.x + av[j].y * avd.y + av[j].z * avd.z + av[j].w * avd.w;
    }
    const int span = (NH == 8) ? 4 : 16;
    #pragma unroll
    for (int stp = 1; stp < span; stp <<= 1) {
        #pragma unroll
        for (int j = 0; j < 4; ++j) {
            ps[j] += __shfl_xor(ps[j], stp);
            pd[j] += __shfl_xor(pd[j], stp);
        }
    }
    if ((cg & (span - 1)) == 0) {
        int hh = (NH == 8) ? (coloff / 16 + (cg >> 2)) : 0;
        #pragma unroll
        for (int j = 0; j < 4; ++j) {
            int rw = orow + j;
            if (rw < n) {
                asrc[(size_t)rw * NH + hh] = ps[j];
                adst[(size_t)rw * NH + hh] = pd[j];
            }
        }
    }
}

// ---------------- layer-1 aggregation: one wave per dst node, two-phase pipelined gather ----------------
__global__ __launch_bounds__(256) void agg1_kernel(const int* __restrict__ rowptr, const int* __restrict__ col,
                                                   const ushort_t* __restrict__ h1b,
                                                   const float* __restrict__ asrc, const float* __restrict__ adst,
                                                   const void* b1, float* __restrict__ hmid, const int* flags) {
    __shared__ float wle[4][8 * 72];
    __shared__ int loff[4][64];
    bool f32 = flags[0] != 0;
    int lane = threadIdx.x & 63, wid = threadIdx.x >> 6;
    int d = blockIdx.x * 4 + wid;
    if (d >= NN) return;                 // per-wave LDS only; no __syncthreads in this kernel
    int start = rowptr[d], end = rowptr[d + 1];
    int hB = lane >> 3;                  // head of dims 2*lane, 2*lane+1
    const float4* dp = (const float4*)(adst + (size_t)d * 8);
    float4 ad0 = dp[0], ad1 = dp[1];     // wave-uniform broadcast load
    const char* hb = (const char*)h1b + lane * 4;   // lane offset hoisted out of loop
    float acc0 = 0.f, acc1 = 0.f, ssum = 0.f;
    for (int chunk = start; chunk < end; chunk += 64) {
        int cnt = min(64, end - chunk);
        int c = (chunk + lane < end) ? col[chunk + lane] : 0;
        loff[wid][lane] = c << 8;        // byte offset of 256B h1b row
        if (lane < cnt) {
            const float4* ap = (const float4*)(asrc + (size_t)c * 8);
            float4 s0 = ap[0], s1 = ap[1];
            wle[wid][0 * 72 + lane] = __expf(lrelu(s0.x + ad0.x));
            wle[wid][1 * 72 + lane] = __expf(lrelu(s0.y + ad0.y));
            wle[wid][2 * 72 + lane] = __expf(lrelu(s0.z + ad0.z));
            wle[wid][3 * 72 + lane] = __expf(lrelu(s0.w + ad0.w));
            wle[wid][4 * 72 + lane] = __expf(lrelu(s1.x + ad1.x));
            wle[wid][5 * 72 + lane] = __expf(lrelu(s1.y + ad1.y));
            wle[wid][6 * 72 + lane] = __expf(lrelu(s1.z + ad1.z));
            wle[wid][7 * 72 + lane] = __expf(lrelu(s1.w + ad1.w));
        }
        #pragma unroll 4
        for (int j = 0; j < cnt; ++j) {
            int off = loff[wid][j];
            float ex = wle[wid][hB * 72 + j];
            unsigned int hv = *(const unsigned int*)(hb + off);
            ssum += ex;
            acc0 = fmaf(ex, __uint_as_float(hv << 16), acc0);
            acc1 = fmaf(ex, __uint_as_float(hv & 0xffff0000u), acc1);
        }
    }
    float inv = 1.f / (ssum + 1e-16f);
    float o0 = fmaf(acc0, inv, ldf(b1, lane * 2, f32));
    float o1 = fmaf(acc1, inv, ldf(b1, lane * 2 + 1, f32));
    o0 = (o0 > 0.f) ? o0 : (__expf(o0) - 1.f);   // ELU
    o1 = (o1 > 0.f) ? o1 : (__expf(o1) - 1.f);
    *(float2*)(hmid + (size_t)d * 128 + lane * 2) = make_float2(o0, o1);
}

// ---------------- layer-2 aggregation (same two-phase scheme) + log_softmax; fp32 output ----------------
__global__ __launch_bounds__(256) void agg2_kernel(const int* __restrict__ rowptr, const int* __restrict__ col,
                                                   const ushort_t* __restrict__ h2b,
                                                   const float* __restrict__ asrc, const float* __restrict__ adst,
                                                   const void* b2, float* __restrict__ out, const int* flags) {
    __shared__ float wle[4][64];
    __shared__ int loff[4][64];
    bool f32 = flags[0] != 0;
    int lane = threadIdx.x & 63, wid = threadIdx.x >> 6;
    int d = blockIdx.x * 4 + wid;
    if (d >= NN) return;
    int start = rowptr[d], end = rowptr[d + 1];
    float ad = adst[d];
    const char* hb = (const char*)h2b + lane * 2;
    float acc = 0.f, ssum = 0.f;
    for (int chunk = start; chunk < end; chunk += 64) {
        int cnt = min(64, end - chunk);
        int c = (chunk + lane < end) ? col[chunk + lane] : 0;
        loff[wid][lane] = c << 7;        // byte offset of 128B h2b row
        if (lane < cnt) wle[wid][lane] = __expf(lrelu(asrc[c] + ad));
        #pragma unroll 4
        for (int j = 0; j < cnt; ++j) {
            int off = loff[wid][j];
            float ex = wle[wid][j];
            float hv = bf2f(*(const ushort_t*)(hb + off));
            ssum += ex;
            acc = fmaf(ex, hv, acc);
        }
    }
    float o = acc / (ssum + 1e-16f) + ldf(b2, lane, f32);
    // log_softmax across 64 lanes
    float mm = o;
    #pragma unroll
    for (int off = 1; off < 64; off <<= 1) mm = fmaxf(mm, __shfl_xor(mm, off));
    float texp = __expf(o - mm);
    float ts = texp;
    #pragma unroll
    for (int off = 1; off < 64; off <<= 1) ts += __shfl_xor(ts, off);
    float ls = o - mm - __logf(ts);
    out[(size_t)d * 64 + lane] = o;
    out[(size_t)NN * 64 + (size_t)d * 64 + lane] = ls;
}

extern "C" void kernel_launch(void* const* d_in, const int* in_sizes, int n_in,
                              void* d_out, int out_size, void* d_ws, size_t ws_size,
                              hipStream_t stream) {
    const void* x   = d_in[0];
    const int*  ei  = (const int*)d_in[1];
    const void* W1  = d_in[2];
    const void* as1 = d_in[3];
    const void* ad1 = d_in[4];
    const void* b1  = d_in[5];
    const void* W2  = d_in[6];
    const void* as2 = d_in[7];
    const void* ad2 = d_in[8];
    const void* b2  = d_in[9];
    float* out = (float*)d_out;

    char* w = (char*)d_ws;
    auto alloc = [&](size_t bytes) {
        void* p = (void*)w;
        w += (bytes + 255) & ~(size_t)255;
        return p;
    };
    int* flags    = (int*)alloc(256);
    int* deg8     = (int*)alloc((size_t)8 * NN * 4);
    int* rowptr   = (int*)alloc((size_t)(NN + 1) * 4);
    int* chunksum = (int*)alloc((size_t)NCH * 4);
    int* chunkoff = (int*)alloc((size_t)NCH * 4);
    int* rank     = (int*)alloc((size_t)ET * 4);
    int* colx     = (int*)alloc((size_t)ET * 4);
    ushort_t* h1b = (ushort_t*)alloc((size_t)NN * 128 * 2);
    float* asrc1  = (float*)alloc((size_t)NN * 8 * 4);
    float* adst1  = (float*)alloc((size_t)NN * 8 * 4);
    float* hmid   = (float*)alloc((size_t)NN * 128 * 4);
    ushort_t* h2b = (ushort_t*)alloc((size_t)NN * 64 * 2);
    float* asrc2  = (float*)alloc((size_t)NN * 4);
    float* adst2  = (float*)alloc((size_t)NN * 4);

    sniff_kernel<<<1, 256, 0, stream>>>((const unsigned int*)x, ei, flags);

    hipMemsetAsync(deg8, 0, (size_t)8 * NN * 4, stream);
    degree_rank_kernel<<<(ET + 255) / 256, 256, 0, stream>>>(ei, deg8, rank, flags);
    scanA_kernel<<<NCH, 256, 0, stream>>>(deg8, chunksum);
    scanB_kernel<<<1, 256, 0, stream>>>(chunksum, chunkoff, rowptr);
    scanC_kernel<<<NCH, 256, 0, stream>>>(deg8, rowptr, chunkoff);
    fill_kernel<<<(ET + 255) / 256, 256, 0, stream>>>(ei, deg8, rank, colx, flags);

    dim3 g1((NN + 63) / 64, 2);
    gemm64_kernel<true, 8><<<g1, 256, 0, stream>>>(x, W1, as1, ad1, h1b, asrc1, adst1, NN, 128, 128, flags);
    agg1_kernel<<<(NN + 3) / 4, 256, 0, stream>>>(rowptr, colx, h1b, asrc1, adst1, b1, hmid, flags);

    dim3 g2((NN + 63) / 64, 1);
    gemm64_kernel<false, 1><<<g2, 256, 0, stream>>>((const void*)hmid, W2, as2, ad2, h2b, asrc2, adst2, NN, 64, 64, flags);
    agg2_kernel<<<(NN + 3) / 4, 256, 0, stream>>>(rowptr, colx, h2b, asrc2, adst2, b2, out, flags);
}

// Round 9
// 271.461 us; speedup vs baseline: 1.1504x; 1.0126x over previous
//
#include <hip/hip_runtime.h>

#define NN 50000
#define EE 800000
#define ET (EE + NN)
#define NCH ((NN + 255) / 256)   // 196 chunks of 256 nodes

typedef unsigned short ushort_t;
using bf16x8 = __attribute__((ext_vector_type(8))) short;
using f32x4  = __attribute__((ext_vector_type(4))) float;

__device__ __forceinline__ float bf2f(ushort_t u) {
    return __uint_as_float(((unsigned int)u) << 16);
}
__device__ __forceinline__ ushort_t f2bf(float f) {
    unsigned int u = __float_as_uint(f);
    u += 0x7fffu + ((u >> 16) & 1u);
    return (ushort_t)(u >> 16);
}
__device__ __forceinline__ float lrelu(float e) {
    return fmaxf(e, 0.f) + 0.2f * fminf(e, 0.f);
}
// load float input that may be fp32 or bf16, per sniffed flag
__device__ __forceinline__ float ldf(const void* p, int i, bool f32) {
    return f32 ? ((const float*)p)[i] : bf2f(((const ushort_t*)p)[i]);
}

// ---------------- dtype sniffer: flags[0]=float inputs are fp32, flags[1]=edge_index is int64 ----------------
__global__ __launch_bounds__(256) void sniff_kernel(const unsigned int* xw, const int* eiw, int* flags) {
    __shared__ int cnt0, cnt1;
    int t = threadIdx.x;
    if (t == 0) { cnt0 = 0; cnt1 = 0; }
    __syncthreads();
    float v = __uint_as_float(xw[t]);
    float a = fabsf(v);
    if ((a > 1e-6f && a < 1e6f) || v == 0.f) atomicAdd(&cnt0, 1);
    if (eiw[2 * t + 1] != 0) atomicAdd(&cnt1, 1);
    __syncthreads();
    if (t == 0) {
        flags[0] = (cnt0 >= 192) ? 1 : 0;
        flags[1] = (cnt1 <= 16) ? 1 : 0;
    }
}

// ---------------- CSR build ----------------
__device__ __forceinline__ void edge_sd(const int* ei, int i, bool i64, int& s, int& d) {
    if (i < EE) {
        if (i64) { s = ei[2 * i]; d = ei[2 * (EE + i)]; }
        else     { s = ei[i];     d = ei[EE + i]; }
    } else {
        s = d = i - EE;
    }
}

// degree + rank in one pass; 8 XCD-local histogram slices (g = blockIdx&7 tracks the
// hardware's round-robin blockIdx->XCD map) so atomic lines stay in one L2.
__global__ __launch_bounds__(256) void degree_rank_kernel(const int* ei, int* deg8, int* rank, const int* flags) {
    int i = blockIdx.x * 256 + threadIdx.x;
    if (i >= ET) return;
    bool i64 = flags[1] != 0;
    int g = blockIdx.x & 7;
    int s, d;
    edge_sd(ei, i, i64, s, d);
    rank[i] = atomicAdd(&deg8[(size_t)g * NN + d], 1);
}

// ---- 3-phase parallel scan over 196 chunks of 256 nodes ----
__global__ __launch_bounds__(256) void scanA_kernel(const int* __restrict__ deg8, int* __restrict__ chunksum) {
    __shared__ int wsum[4];
    int t = threadIdx.x;
    int node = blockIdx.x * 256 + t;
    int v = 0;
    if (node < NN) {
        #pragma unroll
        for (int g = 0; g < 8; ++g) v += deg8[(size_t)g * NN + node];
    }
    int lane = t & 63, wid = t >> 6;
    #pragma unroll
    for (int off = 1; off < 64; off <<= 1) v += __shfl_xor(v, off);
    if (lane == 0) wsum[wid] = v;
    __syncthreads();
    if (t == 0) chunksum[blockIdx.x] = wsum[0] + wsum[1] + wsum[2] + wsum[3];
}

__global__ __launch_bounds__(256) void scanB_kernel(const int* __restrict__ chunksum, int* __restrict__ chunkoff,
                                                    int* __restrict__ rowptr) {
    __shared__ int wsum[4];
    int t = threadIdx.x;
    int lane = t & 63, wid = t >> 6;
    int v = (t < NCH) ? chunksum[t] : 0;
    int x = v;
    #pragma unroll
    for (int off = 1; off < 64; off <<= 1) {
        int y = __shfl_up(x, off);
        if (lane >= off) x += y;
    }
    if (lane == 63) wsum[wid] = x;
    __syncthreads();
    if (t < 4) {
        int s = wsum[t];
        #pragma unroll
        for (int off = 1; off < 4; off <<= 1) {
            int y = __shfl_up(s, off);
            if (t >= off) s += y;
        }
        wsum[t] = s;
    }
    __syncthreads();
    int incl = x + ((wid > 0) ? wsum[wid - 1] : 0);
    if (t < NCH) chunkoff[t] = incl - v;
    if (t == 255) rowptr[NN] = wsum[3];
}

__global__ __launch_bounds__(256) void scanC_kernel(int* __restrict__ deg8, int* __restrict__ rowptr,
                                                    const int* __restrict__ chunkoff) {
    __shared__ int wsum[4];
    int t = threadIdx.x;
    int node = blockIdx.x * 256 + t;
    int dv[8];
    int v = 0;
    if (node < NN) {
        #pragma unroll
        for (int g = 0; g < 8; ++g) {
            dv[g] = deg8[(size_t)g * NN + node];
            v += dv[g];
        }
    }
    int lane = t & 63, wid = t >> 6;
    int x = v;
    #pragma unroll
    for (int off = 1; off < 64; off <<= 1) {
        int y = __shfl_up(x, off);
        if (lane >= off) x += y;
    }
    if (lane == 63) wsum[wid] = x;
    __syncthreads();
    if (t < 4) {
        int s = wsum[t];
        #pragma unroll
        for (int off = 1; off < 4; off <<= 1) {
            int y = __shfl_up(s, off);
            if (t >= off) s += y;
        }
        wsum[t] = s;
    }
    __syncthreads();
    int excl = x - v + ((wid > 0) ? wsum[wid - 1] : 0);
    if (node < NN) {
        int run = chunkoff[blockIdx.x] + excl;
        rowptr[node] = run;
        #pragma unroll
        for (int g = 0; g < 8; ++g) {
            deg8[(size_t)g * NN + node] = run;
            run += dv[g];
        }
    }
}

// atomic-free fill: pos = deg8off[g][d] + rank[i] (same blockIdx->g map as degree_rank)
__global__ __launch_bounds__(256) void fill_kernel(const int* ei, const int* deg8off, const int* rank,
                                                   int* col, const int* flags) {
    int i = blockIdx.x * 256 + threadIdx.x;
    if (i >= ET) return;
    bool i64 = flags[1] != 0;
    int g = blockIdx.x & 7;
    int s, d;
    edge_sd(ei, i, i64, s, d);
    col[deg8off[(size_t)g * NN + d] + rank[i]] = s;
}

// ---------------- MFMA GEMM + fused alpha epilogue ----------------
// out_bf16[n, NCOL] = A[n,128] @ W[128,NCOL]; asrc/adst per head fused.
// A loaded global->VGPR (cvt fp32->bf16 in flight); W staged bf16 transposed in LDS.
// MFMA 16x16x32_bf16: A[m=lane&15][k=quad*8+j]; C/D col=lane&15, row=quad*4+reg.
template <bool AEXT, int NCOL, int NH>
__global__ __launch_bounds__(256) void mgemm_kernel(const void* Av, const void* Wv,
                                                    const void* a_src, const void* a_dst,
                                                    ushort_t* outb, float* asrc, float* adst,
                                                    int n, const int* flags) {
    constexpr int K = 128;
    constexpr int NCT = NCOL / 16;            // col tiles (8 or 4)
    constexpr int WPAD = 136;                 // k-stride pad: <=2-way LDS banks
    __shared__ __align__(16) ushort_t Wb[NCOL * WPAD];
    bool f32 = flags[0] != 0;
    int t = threadIdx.x;

    // stage W[k][nc] -> Wb[nc][k] bf16 (global reads coalesced over nc)
    for (int i = t; i < K * NCOL; i += 256) {
        int k = i / NCOL, nc = i % NCOL;
        Wb[nc * WPAD + k] = f32 ? f2bf(((const float*)Wv)[k * NCOL + nc])
                                : ((const ushort_t*)Wv)[k * NCOL + nc];
    }
    __syncthreads();

    int lane = t & 63, wid = t >> 6;
    int m = lane & 15, quad = lane >> 4;
    int rbase = blockIdx.x * 64 + wid * 16;
    int row = rbase + m;
    bool rok = row < n;

    f32x4 acc[NCT];
    #pragma unroll
    for (int c = 0; c < NCT; ++c) acc[c] = (f32x4){0.f, 0.f, 0.f, 0.f};

    #pragma unroll
    for (int kk = 0; kk < K; kk += 32) {
        bf16x8 af;
        if (rok) {
            if (AEXT && !f32) {
                af = *(const bf16x8*)((const ushort_t*)Av + (size_t)row * K + kk + quad * 8);
            } else {
                const float* ap = (const float*)Av + (size_t)row * K + kk + quad * 8;
                #pragma unroll
                for (int j = 0; j < 8; ++j) af[j] = (short)f2bf(ap[j]);
            }
        } else {
            af = (bf16x8){0, 0, 0, 0, 0, 0, 0, 0};
        }
        #pragma unroll
        for (int c = 0; c < NCT; ++c) {
            bf16x8 bf = *(const bf16x8*)(&Wb[(c * 16 + m) * WPAD + kk + quad * 8]);
            acc[c] = __builtin_amdgcn_mfma_f32_16x16x32_bf16(af, bf, acc[c], 0, 0, 0);
        }
    }

    // ---- epilogue 1: bf16 store of h tile (C layout: row=quad*4+r, col=c*16+m) ----
    int orow0 = rbase + quad * 4;
    #pragma unroll
    for (int c = 0; c < NCT; ++c) {
        #pragma unroll
        for (int r = 0; r < 4; ++r) {
            int orow = orow0 + r;
            if (orow < n) outb[(size_t)orow * NCOL + c * 16 + m] = f2bf(acc[c][r]);
        }
    }

    // ---- epilogue 2: fused alpha dot products ----
    if (NH == 8) {
        #pragma unroll
        for (int c = 0; c < NCT; ++c) {       // c == head
            float as = ldf(a_src, c * 16 + m, f32);
            float ad = ldf(a_dst, c * 16 + m, f32);
            float ps[4], pd[4];
            #pragma unroll
            for (int r = 0; r < 4; ++r) { ps[r] = acc[c][r] * as; pd[r] = acc[c][r] * ad; }
            #pragma unroll
            for (int stp = 1; stp < 16; stp <<= 1) {
                #pragma unroll
                for (int r = 0; r < 4; ++r) {
                    ps[r] += __shfl_xor(ps[r], stp);
                    pd[r] += __shfl_xor(pd[r], stp);
                }
            }
            if (m == 0) {
                #pragma unroll
                for (int r = 0; r < 4; ++r) {
                    int orow = orow0 + r;
                    if (orow < n) {
                        asrc[(size_t)orow * 8 + c] = ps[r];
                        adst[(size_t)orow * 8 + c] = pd[r];
                    }
                }
            }
        }
    } else {
        float ps[4] = {0.f, 0.f, 0.f, 0.f}, pd[4] = {0.f, 0.f, 0.f, 0.f};
        #pragma unroll
        for (int c = 0; c < NCT; ++c) {
            float as = ldf(a_src, c * 16 + m, f32);
            float ad = ldf(a_dst, c * 16 + m, f32);
            #pragma unroll
            for (int r = 0; r < 4; ++r) {
                ps[r] = fmaf(acc[c][r], as, ps[r]);
                pd[r] = fmaf(acc[c][r], ad, pd[r]);
            }
        }
        #pragma unroll
        for (int stp = 1; stp < 16; stp <<= 1) {
            #pragma unroll
            for (int r = 0; r < 4; ++r) {
                ps[r] += __shfl_xor(ps[r], stp);
                pd[r] += __shfl_xor(pd[r], stp);
            }
        }
        if (m == 0) {
            #pragma unroll
            for (int r = 0; r < 4; ++r) {
                int orow = orow0 + r;
                if (orow < n) { asrc[orow] = ps[r]; adst[orow] = pd[r]; }
            }
        }
    }
}

// ---------------- layer-1 aggregation: one wave per dst node, two-phase pipelined gather ----------------
__global__ __launch_bounds__(256) void agg1_kernel(const int* __restrict__ rowptr, const int* __restrict__ col,
                                                   const ushort_t* __restrict__ h1b,
                                                   const float* __restrict__ asrc, const float* __restrict__ adst,
                                                   const void* b1, float* __restrict__ hmid, const int* flags) {
    __shared__ float wle[4][8 * 72];
    __shared__ int loff[4][64];
    bool f32 = flags[0] != 0;
    int lane = threadIdx.x & 63, wid = threadIdx.x >> 6;
    int d = blockIdx.x * 4 + wid;
    if (d >= NN) return;                 // per-wave LDS only; no __syncthreads in this kernel
    int start = rowptr[d], end = rowptr[d + 1];
    int hB = lane >> 3;                  // head of dims 2*lane, 2*lane+1
    const float4* dp = (const float4*)(adst + (size_t)d * 8);
    float4 ad0 = dp[0], ad1 = dp[1];     // wave-uniform broadcast load
    const char* hb = (const char*)h1b + lane * 4;   // lane offset hoisted out of loop
    float acc0 = 0.f, acc1 = 0.f, ssum = 0.f;
    for (int chunk = start; chunk < end; chunk += 64) {
        int cnt = min(64, end - chunk);
        int c = (chunk + lane < end) ? col[chunk + lane] : 0;
        loff[wid][lane] = c << 8;        // byte offset of 256B h1b row
        if (lane < cnt) {
            const float4* ap = (const float4*)(asrc + (size_t)c * 8);
            float4 s0 = ap[0], s1 = ap[1];
            wle[wid][0 * 72 + lane] = __expf(lrelu(s0.x + ad0.x));
            wle[wid][1 * 72 + lane] = __expf(lrelu(s0.y + ad0.y));
            wle[wid][2 * 72 + lane] = __expf(lrelu(s0.z + ad0.z));
            wle[wid][3 * 72 + lane] = __expf(lrelu(s0.w + ad0.w));
            wle[wid][4 * 72 + lane] = __expf(lrelu(s1.x + ad1.x));
            wle[wid][5 * 72 + lane] = __expf(lrelu(s1.y + ad1.y));
            wle[wid][6 * 72 + lane] = __expf(lrelu(s1.z + ad1.z));
            wle[wid][7 * 72 + lane] = __expf(lrelu(s1.w + ad1.w));
        }
        #pragma unroll 4
        for (int j = 0; j < cnt; ++j) {
            int off = loff[wid][j];
            float ex = wle[wid][hB * 72 + j];
            unsigned int hv = *(const unsigned int*)(hb + off);
            ssum += ex;
            acc0 = fmaf(ex, __uint_as_float(hv << 16), acc0);
            acc1 = fmaf(ex, __uint_as_float(hv & 0xffff0000u), acc1);
        }
    }
    float inv = 1.f / (ssum + 1e-16f);
    float o0 = fmaf(acc0, inv, ldf(b1, lane * 2, f32));
    float o1 = fmaf(acc1, inv, ldf(b1, lane * 2 + 1, f32));
    o0 = (o0 > 0.f) ? o0 : (__expf(o0) - 1.f);   // ELU
    o1 = (o1 > 0.f) ? o1 : (__expf(o1) - 1.f);
    *(float2*)(hmid + (size_t)d * 128 + lane * 2) = make_float2(o0, o1);
}

// ---------------- layer-2 aggregation (same two-phase scheme) + log_softmax; fp32 output ----------------
__global__ __launch_bounds__(256) void agg2_kernel(const int* __restrict__ rowptr, const int* __restrict__ col,
                                                   const ushort_t* __restrict__ h2b,
                                                   const float* __restrict__ asrc, const float* __restrict__ adst,
                                                   const void* b2, float* __restrict__ out, const int* flags) {
    __shared__ float wle[4][64];
    __shared__ int loff[4][64];
    bool f32 = flags[0] != 0;
    int lane = threadIdx.x & 63, wid = threadIdx.x >> 6;
    int d = blockIdx.x * 4 + wid;
    if (d >= NN) return;
    int start = rowptr[d], end = rowptr[d + 1];
    float ad = adst[d];
    const char* hb = (const char*)h2b + lane * 2;
    float acc = 0.f, ssum = 0.f;
    for (int chunk = start; chunk < end; chunk += 64) {
        int cnt = min(64, end - chunk);
        int c = (chunk + lane < end) ? col[chunk + lane] : 0;
        loff[wid][lane] = c << 7;        // byte offset of 128B h2b row
        if (lane < cnt) wle[wid][lane] = __expf(lrelu(asrc[c] + ad));
        #pragma unroll 4
        for (int j = 0; j < cnt; ++j) {
            int off = loff[wid][j];
            float ex = wle[wid][j];
            float hv = bf2f(*(const ushort_t*)(hb + off));
            ssum += ex;
            acc = fmaf(ex, hv, acc);
        }
    }
    float o = acc / (ssum + 1e-16f) + ldf(b2, lane, f32);
    // log_softmax across 64 lanes
    float mm = o;
    #pragma unroll
    for (int off = 1; off < 64; off <<= 1) mm = fmaxf(mm, __shfl_xor(mm, off));
    float texp = __expf(o - mm);
    float ts = texp;
    #pragma unroll
    for (int off = 1; off < 64; off <<= 1) ts += __shfl_xor(ts, off);
    float ls = o - mm - __logf(ts);
    out[(size_t)d * 64 + lane] = o;
    out[(size_t)NN * 64 + (size_t)d * 64 + lane] = ls;
}

extern "C" void kernel_launch(void* const* d_in, const int* in_sizes, int n_in,
                              void* d_out, int out_size, void* d_ws, size_t ws_size,
                              hipStream_t stream) {
    const void* x   = d_in[0];
    const int*  ei  = (const int*)d_in[1];
    const void* W1  = d_in[2];
    const void* as1 = d_in[3];
    const void* ad1 = d_in[4];
    const void* b1  = d_in[5];
    const void* W2  = d_in[6];
    const void* as2 = d_in[7];
    const void* ad2 = d_in[8];
    const void* b2  = d_in[9];
    float* out = (float*)d_out;

    char* w = (char*)d_ws;
    auto alloc = [&](size_t bytes) {
        void* p = (void*)w;
        w += (bytes + 255) & ~(size_t)255;
        return p;
    };
    int* flags    = (int*)alloc(256);
    int* deg8     = (int*)alloc((size_t)8 * NN * 4);
    int* rowptr   = (int*)alloc((size_t)(NN + 1) * 4);
    int* chunksum = (int*)alloc((size_t)NCH * 4);
    int* chunkoff = (int*)alloc((size_t)NCH * 4);
    int* rank     = (int*)alloc((size_t)ET * 4);
    int* colx     = (int*)alloc((size_t)ET * 4);
    ushort_t* h1b = (ushort_t*)alloc((size_t)NN * 128 * 2);
    float* asrc1  = (float*)alloc((size_t)NN * 8 * 4);
    float* adst1  = (float*)alloc((size_t)NN * 8 * 4);
    float* hmid   = (float*)alloc((size_t)NN * 128 * 4);
    ushort_t* h2b = (ushort_t*)alloc((size_t)NN * 64 * 2);
    float* asrc2  = (float*)alloc((size_t)NN * 4);
    float* adst2  = (float*)alloc((size_t)NN * 4);

    sniff_kernel<<<1, 256, 0, stream>>>((const unsigned int*)x, ei, flags);

    hipMemsetAsync(deg8, 0, (size_t)8 * NN * 4, stream);
    degree_rank_kernel<<<(ET + 255) / 256, 256, 0, stream>>>(ei, deg8, rank, flags);
    scanA_kernel<<<NCH, 256, 0, stream>>>(deg8, chunksum);
    scanB_kernel<<<1, 256, 0, stream>>>(chunksum, chunkoff, rowptr);
    scanC_kernel<<<NCH, 256, 0, stream>>>(deg8, rowptr, chunkoff);
    fill_kernel<<<(ET + 255) / 256, 256, 0, stream>>>(ei, deg8, rank, colx, flags);

    int gblocks = (NN + 63) / 64;
    mgemm_kernel<true, 128, 8><<<gblocks, 256, 0, stream>>>(x, W1, as1, ad1, h1b, asrc1, adst1, NN, flags);
    agg1_kernel<<<(NN + 3) / 4, 256, 0, stream>>>(rowptr, colx, h1b, asrc1, adst1, b1, hmid, flags);

    mgemm_kernel<false, 64, 1><<<gblocks, 256, 0, stream>>>((const void*)hmid, W2, as2, ad2, h2b, asrc2, adst2, NN, flags);
    agg2_kernel<<<(NN + 3) / 4, 256, 0, stream>>>(rowptr, colx, h2b, asrc2, adst2, b2, out, flags);
}

// Round 10
// 265.142 us; speedup vs baseline: 1.1779x; 1.0238x over previous
//
#include <hip/hip_runtime.h>

#define NN 50000
#define EE 800000
#define ET (EE + NN)
#define NCH ((NN + 255) / 256)   // 196 chunks of 256 nodes

typedef unsigned short ushort_t;
using bf16x8 = __attribute__((ext_vector_type(8))) short;
using f32x4  = __attribute__((ext_vector_type(4))) float;

__device__ __forceinline__ float bf2f(ushort_t u) {
    return __uint_as_float(((unsigned int)u) << 16);
}
__device__ __forceinline__ ushort_t f2bf(float f) {
    unsigned int u = __float_as_uint(f);
    u += 0x7fffu + ((u >> 16) & 1u);
    return (ushort_t)(u >> 16);
}
__device__ __forceinline__ float lrelu(float e) {
    return fmaxf(e, 0.f) + 0.2f * fminf(e, 0.f);
}
// load float input that may be fp32 or bf16, per sniffed flag
__device__ __forceinline__ float ldf(const void* p, int i, bool f32) {
    return f32 ? ((const float*)p)[i] : bf2f(((const ushort_t*)p)[i]);
}

// ---------------- dtype sniffer: flags[0]=float inputs are fp32, flags[1]=edge_index is int64 ----------------
__global__ __launch_bounds__(256) void sniff_kernel(const unsigned int* xw, const int* eiw, int* flags) {
    __shared__ int cnt0, cnt1;
    int t = threadIdx.x;
    if (t == 0) { cnt0 = 0; cnt1 = 0; }
    __syncthreads();
    float v = __uint_as_float(xw[t]);
    float a = fabsf(v);
    if ((a > 1e-6f && a < 1e6f) || v == 0.f) atomicAdd(&cnt0, 1);
    if (eiw[2 * t + 1] != 0) atomicAdd(&cnt1, 1);
    __syncthreads();
    if (t == 0) {
        flags[0] = (cnt0 >= 192) ? 1 : 0;
        flags[1] = (cnt1 <= 16) ? 1 : 0;
    }
}

// ---------------- CSR build ----------------
__device__ __forceinline__ void edge_sd(const int* ei, int i, bool i64, int& s, int& d) {
    if (i < EE) {
        if (i64) { s = ei[2 * i]; d = ei[2 * (EE + i)]; }
        else     { s = ei[i];     d = ei[EE + i]; }
    } else {
        s = d = i - EE;
    }
}

// degree + rank in one pass; 8 XCD-local histogram slices (g = blockIdx&7 tracks the
// hardware's round-robin blockIdx->XCD map) so atomic lines stay in one L2.
__global__ __launch_bounds__(256) void degree_rank_kernel(const int* ei, int* deg8, int* rank, const int* flags) {
    int i = blockIdx.x * 256 + threadIdx.x;
    if (i >= ET) return;
    bool i64 = flags[1] != 0;
    int g = blockIdx.x & 7;
    int s, d;
    edge_sd(ei, i, i64, s, d);
    rank[i] = atomicAdd(&deg8[(size_t)g * NN + d], 1);
}

// ---- 3-phase parallel scan over 196 chunks of 256 nodes ----
__global__ __launch_bounds__(256) void scanA_kernel(const int* __restrict__ deg8, int* __restrict__ chunksum) {
    __shared__ int wsum[4];
    int t = threadIdx.x;
    int node = blockIdx.x * 256 + t;
    int v = 0;
    if (node < NN) {
        #pragma unroll
        for (int g = 0; g < 8; ++g) v += deg8[(size_t)g * NN + node];
    }
    int lane = t & 63, wid = t >> 6;
    #pragma unroll
    for (int off = 1; off < 64; off <<= 1) v += __shfl_xor(v, off);
    if (lane == 0) wsum[wid] = v;
    __syncthreads();
    if (t == 0) chunksum[blockIdx.x] = wsum[0] + wsum[1] + wsum[2] + wsum[3];
}

__global__ __launch_bounds__(256) void scanB_kernel(const int* __restrict__ chunksum, int* __restrict__ chunkoff,
                                                    int* __restrict__ rowptr) {
    __shared__ int wsum[4];
    int t = threadIdx.x;
    int lane = t & 63, wid = t >> 6;
    int v = (t < NCH) ? chunksum[t] : 0;
    int x = v;
    #pragma unroll
    for (int off = 1; off < 64; off <<= 1) {
        int y = __shfl_up(x, off);
        if (lane >= off) x += y;
    }
    if (lane == 63) wsum[wid] = x;
    __syncthreads();
    if (t < 4) {
        int s = wsum[t];
        #pragma unroll
        for (int off = 1; off < 4; off <<= 1) {
            int y = __shfl_up(s, off);
            if (t >= off) s += y;
        }
        wsum[t] = s;
    }
    __syncthreads();
    int incl = x + ((wid > 0) ? wsum[wid - 1] : 0);
    if (t < NCH) chunkoff[t] = incl - v;
    if (t == 255) rowptr[NN] = wsum[3];
}

__global__ __launch_bounds__(256) void scanC_kernel(int* __restrict__ deg8, int* __restrict__ rowptr,
                                                    const int* __restrict__ chunkoff) {
    __shared__ int wsum[4];
    int t = threadIdx.x;
    int node = blockIdx.x * 256 + t;
    int dv[8];
    int v = 0;
    if (node < NN) {
        #pragma unroll
        for (int g = 0; g < 8; ++g) {
            dv[g] = deg8[(size_t)g * NN + node];
            v += dv[g];
        }
    }
    int lane = t & 63, wid = t >> 6;
    int x = v;
    #pragma unroll
    for (int off = 1; off < 64; off <<= 1) {
        int y = __shfl_up(x, off);
        if (lane >= off) x += y;
    }
    if (lane == 63) wsum[wid] = x;
    __syncthreads();
    if (t < 4) {
        int s = wsum[t];
        #pragma unroll
        for (int off = 1; off < 4; off <<= 1) {
            int y = __shfl_up(s, off);
            if (t >= off) s += y;
        }
        wsum[t] = s;
    }
    __syncthreads();
    int excl = x - v + ((wid > 0) ? wsum[wid - 1] : 0);
    if (node < NN) {
        int run = chunkoff[blockIdx.x] + excl;
        rowptr[node] = run;
        #pragma unroll
        for (int g = 0; g < 8; ++g) {
            deg8[(size_t)g * NN + node] = run;
            run += dv[g];
        }
    }
}

// atomic-free fill: pos = deg8off[g][d] + rank[i] (same blockIdx->g map as degree_rank)
__global__ __launch_bounds__(256) void fill_kernel(const int* ei, const int* deg8off, const int* rank,
                                                   int* col, const int* flags) {
    int i = blockIdx.x * 256 + threadIdx.x;
    if (i >= ET) return;
    bool i64 = flags[1] != 0;
    int g = blockIdx.x & 7;
    int s, d;
    edge_sd(ei, i, i64, s, d);
    col[deg8off[(size_t)g * NN + d] + rank[i]] = s;
}

// ---------------- W pre-transpose to bf16: Wt[nc][k] (k-major rows of 128) ----------------
__global__ __launch_bounds__(256) void wtprep_kernel(const void* W1v, const void* W2v,
                                                     ushort_t* Wt1, ushort_t* Wt2, const int* flags) {
    bool f32 = flags[0] != 0;
    int i = blockIdx.x * 256 + threadIdx.x;
    if (i < 128 * 128) {                       // W1[k][nc], k=i>>7, nc=i&127 (coalesced read)
        int k = i >> 7, nc = i & 127;
        ushort_t v = f32 ? f2bf(((const float*)W1v)[i]) : ((const ushort_t*)W1v)[i];
        Wt1[nc * 128 + k] = v;
    }
    int j = i - 128 * 128;
    if (j >= 0 && j < 128 * 64) {              // W2[k][nc], k=j>>6, nc=j&63
        int k = j >> 6, nc = j & 63;
        ushort_t v = f32 ? f2bf(((const float*)W2v)[j]) : ((const ushort_t*)W2v)[j];
        Wt2[nc * 128 + k] = v;
    }
}

// ---------------- MFMA GEMM, no LDS: A global->VGPR streamed, B (Wt) global->VGPR L2-resident ----------------
// out_bf16[n, NCOL] = A[n,128] @ W[128,NCOL]; asrc/adst per head fused.
// MFMA 16x16x32_bf16: A[m=lane&15][k=quad*8+j]; B[k][n=lane&15]; C/D col=lane&15, row=quad*4+reg.
template <bool AEXT, int NCOL, int NH>
__global__ __launch_bounds__(256) void mgemm_kernel(const void* Av, const ushort_t* __restrict__ Wt,
                                                    const void* a_src, const void* a_dst,
                                                    ushort_t* outb, float* asrc, float* adst,
                                                    int n, const int* flags) {
    constexpr int K = 128;
    constexpr int NCT = NCOL / 16;            // col tiles (8 or 4)
    bool f32 = flags[0] != 0;
    bool af32 = AEXT && f32;                  // internal A (hmid) is always bf16
    int t = threadIdx.x;
    int lane = t & 63, wid = t >> 6;
    int m = lane & 15, quad = lane >> 4;
    int rbase = blockIdx.x * 64 + wid * 16;
    int row = rbase + m;
    bool rok = row < n;

    // ---- A fragments: all 4 kk chunks loaded up front (max MLP) ----
    bf16x8 af[4];
    if (rok) {
        if (!af32) {
            const ushort_t* ap = (const ushort_t*)Av + (size_t)row * K + quad * 8;
            #pragma unroll
            for (int kk = 0; kk < 4; ++kk) af[kk] = *(const bf16x8*)(ap + kk * 32);
        } else {
            const float* ap = (const float*)Av + (size_t)row * K + quad * 8;
            #pragma unroll
            for (int kk = 0; kk < 4; ++kk) {
                float4 q0 = *(const float4*)(ap + kk * 32);
                float4 q1 = *(const float4*)(ap + kk * 32 + 4);
                bf16x8 v;
                v[0] = (short)f2bf(q0.x); v[1] = (short)f2bf(q0.y);
                v[2] = (short)f2bf(q0.z); v[3] = (short)f2bf(q0.w);
                v[4] = (short)f2bf(q1.x); v[5] = (short)f2bf(q1.y);
                v[6] = (short)f2bf(q1.z); v[7] = (short)f2bf(q1.w);
                af[kk] = v;
            }
        }
    } else {
        #pragma unroll
        for (int kk = 0; kk < 4; ++kk) af[kk] = (bf16x8){0, 0, 0, 0, 0, 0, 0, 0};
    }

    f32x4 acc[NCT];
    #pragma unroll
    for (int c = 0; c < NCT; ++c) acc[c] = (f32x4){0.f, 0.f, 0.f, 0.f};

    // B fragments: Wt[(c*16+m)][kk*32 + quad*8 ..+8] — wave covers contiguous 4KB, L1/L2-hit
    const ushort_t* wp = Wt + (size_t)m * K + quad * 8;
    #pragma unroll
    for (int c = 0; c < NCT; ++c) {
        const ushort_t* wc = wp + (size_t)c * 16 * K;
        #pragma unroll
        for (int kk = 0; kk < 4; ++kk) {
            bf16x8 bf = *(const bf16x8*)(wc + kk * 32);
            acc[c] = __builtin_amdgcn_mfma_f32_16x16x32_bf16(af[kk], bf, acc[c], 0, 0, 0);
        }
    }

    // ---- epilogue 1: bf16 store of h tile (C layout: row=quad*4+r, col=c*16+m) ----
    int orow0 = rbase + quad * 4;
    #pragma unroll
    for (int c = 0; c < NCT; ++c) {
        #pragma unroll
        for (int r = 0; r < 4; ++r) {
            int orow = orow0 + r;
            if (orow < n) outb[(size_t)orow * NCOL + c * 16 + m] = f2bf(acc[c][r]);
        }
    }

    // ---- epilogue 2: fused alpha dot products ----
    if (NH == 8) {
        #pragma unroll
        for (int c = 0; c < NCT; ++c) {       // c == head
            float as = ldf(a_src, c * 16 + m, f32);
            float ad = ldf(a_dst, c * 16 + m, f32);
            float ps[4], pd[4];
            #pragma unroll
            for (int r = 0; r < 4; ++r) { ps[r] = acc[c][r] * as; pd[r] = acc[c][r] * ad; }
            #pragma unroll
            for (int stp = 1; stp < 16; stp <<= 1) {
                #pragma unroll
                for (int r = 0; r < 4; ++r) {
                    ps[r] += __shfl_xor(ps[r], stp);
                    pd[r] += __shfl_xor(pd[r], stp);
                }
            }
            if (m == 0) {
                #pragma unroll
                for (int r = 0; r < 4; ++r) {
                    int orow = orow0 + r;
                    if (orow < n) {
                        asrc[(size_t)orow * 8 + c] = ps[r];
                        adst[(size_t)orow * 8 + c] = pd[r];
                    }
                }
            }
        }
    } else {
        float ps[4] = {0.f, 0.f, 0.f, 0.f}, pd[4] = {0.f, 0.f, 0.f, 0.f};
        #pragma unroll
        for (int c = 0; c < NCT; ++c) {
            float as = ldf(a_src, c * 16 + m, f32);
            float ad = ldf(a_dst, c * 16 + m, f32);
            #pragma unroll
            for (int r = 0; r < 4; ++r) {
                ps[r] = fmaf(acc[c][r], as, ps[r]);
                pd[r] = fmaf(acc[c][r], ad, pd[r]);
            }
        }
        #pragma unroll
        for (int stp = 1; stp < 16; stp <<= 1) {
            #pragma unroll
            for (int r = 0; r < 4; ++r) {
                ps[r] += __shfl_xor(ps[r], stp);
                pd[r] += __shfl_xor(pd[r], stp);
            }
        }
        if (m == 0) {
            #pragma unroll
            for (int r = 0; r < 4; ++r) {
                int orow = orow0 + r;
                if (orow < n) { asrc[orow] = ps[r]; adst[orow] = pd[r]; }
            }
        }
    }
}

// ---------------- layer-1 aggregation: one wave per dst node, two-phase pipelined gather ----------------
// hmid output now bf16 (packed pair per uint store)
__global__ __launch_bounds__(256) void agg1_kernel(const int* __restrict__ rowptr, const int* __restrict__ col,
                                                   const ushort_t* __restrict__ h1b,
                                                   const float* __restrict__ asrc, const float* __restrict__ adst,
                                                   const void* b1, ushort_t* __restrict__ hmidb, const int* flags) {
    __shared__ float wle[4][8 * 72];
    __shared__ int loff[4][64];
    bool f32 = flags[0] != 0;
    int lane = threadIdx.x & 63, wid = threadIdx.x >> 6;
    int d = blockIdx.x * 4 + wid;
    if (d >= NN) return;                 // per-wave LDS only; no __syncthreads in this kernel
    int start = rowptr[d], end = rowptr[d + 1];
    int hB = lane >> 3;                  // head of dims 2*lane, 2*lane+1
    const float4* dp = (const float4*)(adst + (size_t)d * 8);
    float4 ad0 = dp[0], ad1 = dp[1];     // wave-uniform broadcast load
    const char* hb = (const char*)h1b + lane * 4;   // lane offset hoisted out of loop
    float acc0 = 0.f, acc1 = 0.f, ssum = 0.f;
    for (int chunk = start; chunk < end; chunk += 64) {
        int cnt = min(64, end - chunk);
        int c = (chunk + lane < end) ? col[chunk + lane] : 0;
        loff[wid][lane] = c << 8;        // byte offset of 256B h1b row
        if (lane < cnt) {
            const float4* ap = (const float4*)(asrc + (size_t)c * 8);
            float4 s0 = ap[0], s1 = ap[1];
            wle[wid][0 * 72 + lane] = __expf(lrelu(s0.x + ad0.x));
            wle[wid][1 * 72 + lane] = __expf(lrelu(s0.y + ad0.y));
            wle[wid][2 * 72 + lane] = __expf(lrelu(s0.z + ad0.z));
            wle[wid][3 * 72 + lane] = __expf(lrelu(s0.w + ad0.w));
            wle[wid][4 * 72 + lane] = __expf(lrelu(s1.x + ad1.x));
            wle[wid][5 * 72 + lane] = __expf(lrelu(s1.y + ad1.y));
            wle[wid][6 * 72 + lane] = __expf(lrelu(s1.z + ad1.z));
            wle[wid][7 * 72 + lane] = __expf(lrelu(s1.w + ad1.w));
        }
        #pragma unroll 4
        for (int j = 0; j < cnt; ++j) {
            int off = loff[wid][j];
            float ex = wle[wid][hB * 72 + j];
            unsigned int hv = *(const unsigned int*)(hb + off);
            ssum += ex;
            acc0 = fmaf(ex, __uint_as_float(hv << 16), acc0);
            acc1 = fmaf(ex, __uint_as_float(hv & 0xffff0000u), acc1);
        }
    }
    float inv = 1.f / (ssum + 1e-16f);
    float o0 = fmaf(acc0, inv, ldf(b1, lane * 2, f32));
    float o1 = fmaf(acc1, inv, ldf(b1, lane * 2 + 1, f32));
    o0 = (o0 > 0.f) ? o0 : (__expf(o0) - 1.f);   // ELU
    o1 = (o1 > 0.f) ? o1 : (__expf(o1) - 1.f);
    unsigned int pk = ((unsigned int)f2bf(o1) << 16) | (unsigned int)f2bf(o0);
    *(unsigned int*)(hmidb + (size_t)d * 128 + lane * 2) = pk;
}

// ---------------- layer-2 aggregation (same two-phase scheme) + log_softmax; fp32 output ----------------
__global__ __launch_bounds__(256) void agg2_kernel(const int* __restrict__ rowptr, const int* __restrict__ col,
                                                   const ushort_t* __restrict__ h2b,
                                                   const float* __restrict__ asrc, const float* __restrict__ adst,
                                                   const void* b2, float* __restrict__ out, const int* flags) {
    __shared__ float wle[4][64];
    __shared__ int loff[4][64];
    bool f32 = flags[0] != 0;
    int lane = threadIdx.x & 63, wid = threadIdx.x >> 6;
    int d = blockIdx.x * 4 + wid;
    if (d >= NN) return;
    int start = rowptr[d], end = rowptr[d + 1];
    float ad = adst[d];
    const char* hb = (const char*)h2b + lane * 2;
    float acc = 0.f, ssum = 0.f;
    for (int chunk = start; chunk < end; chunk += 64) {
        int cnt = min(64, end - chunk);
        int c = (chunk + lane < end) ? col[chunk + lane] : 0;
        loff[wid][lane] = c << 7;        // byte offset of 128B h2b row
        if (lane < cnt) wle[wid][lane] = __expf(lrelu(asrc[c] + ad));
        #pragma unroll 4
        for (int j = 0; j < cnt; ++j) {
            int off = loff[wid][j];
            float ex = wle[wid][j];
            float hv = bf2f(*(const ushort_t*)(hb + off));
            ssum += ex;
            acc = fmaf(ex, hv, acc);
        }
    }
    float o = acc / (ssum + 1e-16f) + ldf(b2, lane, f32);
    // log_softmax across 64 lanes
    float mm = o;
    #pragma unroll
    for (int off = 1; off < 64; off <<= 1) mm = fmaxf(mm, __shfl_xor(mm, off));
    float texp = __expf(o - mm);
    float ts = texp;
    #pragma unroll
    for (int off = 1; off < 64; off <<= 1) ts += __shfl_xor(ts, off);
    float ls = o - mm - __logf(ts);
    out[(size_t)d * 64 + lane] = o;
    out[(size_t)NN * 64 + (size_t)d * 64 + lane] = ls;
}

extern "C" void kernel_launch(void* const* d_in, const int* in_sizes, int n_in,
                              void* d_out, int out_size, void* d_ws, size_t ws_size,
                              hipStream_t stream) {
    const void* x   = d_in[0];
    const int*  ei  = (const int*)d_in[1];
    const void* W1  = d_in[2];
    const void* as1 = d_in[3];
    const void* ad1 = d_in[4];
    const void* b1  = d_in[5];
    const void* W2  = d_in[6];
    const void* as2 = d_in[7];
    const void* ad2 = d_in[8];
    const void* b2  = d_in[9];
    float* out = (float*)d_out;

    char* w = (char*)d_ws;
    auto alloc = [&](size_t bytes) {
        void* p = (void*)w;
        w += (bytes + 255) & ~(size_t)255;
        return p;
    };
    int* flags    = (int*)alloc(256);
    int* deg8     = (int*)alloc((size_t)8 * NN * 4);
    int* rowptr   = (int*)alloc((size_t)(NN + 1) * 4);
    int* chunksum = (int*)alloc((size_t)NCH * 4);
    int* chunkoff = (int*)alloc((size_t)NCH * 4);
    int* rank     = (int*)alloc((size_t)ET * 4);
    int* colx     = (int*)alloc((size_t)ET * 4);
    ushort_t* Wt1 = (ushort_t*)alloc((size_t)128 * 128 * 2);
    ushort_t* Wt2 = (ushort_t*)alloc((size_t)64 * 128 * 2);
    ushort_t* h1b = (ushort_t*)alloc((size_t)NN * 128 * 2);
    float* asrc1  = (float*)alloc((size_t)NN * 8 * 4);
    float* adst1  = (float*)alloc((size_t)NN * 8 * 4);
    ushort_t* hmidb = (ushort_t*)alloc((size_t)NN * 128 * 2);
    ushort_t* h2b = (ushort_t*)alloc((size_t)NN * 64 * 2);
    float* asrc2  = (float*)alloc((size_t)NN * 4);
    float* adst2  = (float*)alloc((size_t)NN * 4);

    sniff_kernel<<<1, 256, 0, stream>>>((const unsigned int*)x, ei, flags);

    hipMemsetAsync(deg8, 0, (size_t)8 * NN * 4, stream);
    degree_rank_kernel<<<(ET + 255) / 256, 256, 0, stream>>>(ei, deg8, rank, flags);
    scanA_kernel<<<NCH, 256, 0, stream>>>(deg8, chunksum);
    scanB_kernel<<<1, 256, 0, stream>>>(chunksum, chunkoff, rowptr);
    scanC_kernel<<<NCH, 256, 0, stream>>>(deg8, rowptr, chunkoff);
    fill_kernel<<<(ET + 255) / 256, 256, 0, stream>>>(ei, deg8, rank, colx, flags);
    wtprep_kernel<<<(128 * 128 + 128 * 64 + 255) / 256, 256, 0, stream>>>(W1, W2, Wt1, Wt2, flags);

    int gblocks = (NN + 63) / 64;
    mgemm_kernel<true, 128, 8><<<gblocks, 256, 0, stream>>>(x, Wt1, as1, ad1, h1b, asrc1, adst1, NN, flags);
    agg1_kernel<<<(NN + 3) / 4, 256, 0, stream>>>(rowptr, colx, h1b, asrc1, adst1, b1, hmidb, flags);

    mgemm_kernel<false, 64, 1><<<gblocks, 256, 0, stream>>>((const void*)hmidb, Wt2, as2, ad2, h2b, asrc2, adst2, NN, flags);
    agg2_kernel<<<(NN + 3) / 4, 256, 0, stream>>>(rowptr, colx, h2b, asrc2, adst2, b2, out, flags);
}